// Round 20
// baseline (111.105 us; speedup 1.0000x reference)
//
#include <hip/hip_runtime.h>

// ---------------------------------------------------------------------------
// Fused attention block, bf16 MFMA pipeline.
// ws layout (needs 40 MB):
//   [0,8M)    xb   : x as bf16 [4096][1024], ROW-CHUNK-SWIZZLED (reused as Ob)
//   [8M,14M)  WqT  : W_qkv^T bf16 [3072][1024], swizzled
//   [14M,16M) WpT  : W_proj^T bf16 [1024][1024], swizzled
//   [16M,24M) Qb   : [32][2048][64] bf16  (pre-scaled by SCALE*log2e)
//   [24M,32M) Kb   : [32][32 tiles][64x64] bf16, XOR-chunk-swizzled tiles
//   [32M,40M) Vt   : [32][32 tiles][64x64] bf16, transposed + swizzled tiles
//
// ROW-CHUNK SWIZZLE (GEMM operands, row length 1024): element (r,d) stored at
//   r*1024 + (((d>>3) ^ (r&7))<<3) + (d&7)  -> 0 LDS bank conflicts (R12).
//
// qkv GEMM (R19): 256x192 tile, grid 256 = exactly 1 block/CU, 8-phase
// counted-vmcnt schedule, per-region LDS-bounce epilogue.
//
// attn (R20): 2-WAVE BLOCKS (128 thr, 64 q-rows), grid 1024 = exactly 4
// blocks/CU (LDS 40KB: K/V dbuf 32 + P 2x4). R19 counters showed attn is
// latency-exposed (2 waves/SIMD, ~22% SIMD busy, LDS only ~50% busy); 4
// independent small blocks per CU give phase-diverse issue without the
// traffic penalty of smaller q-tiles. Same per-wave compute as R8 config.
// ---------------------------------------------------------------------------

typedef __bf16 bf16_t;
typedef __bf16 bf16x2 __attribute__((ext_vector_type(2)));
typedef __bf16 bf16x4 __attribute__((ext_vector_type(4)));
typedef __bf16 bf16x8 __attribute__((ext_vector_type(8)));
typedef float  f32x4  __attribute__((ext_vector_type(4)));

#define NTOK 2048
#define DIM  1024
#define NH   16
#define HD   64
#define SCL2 0.18033688011112042f   // (1/8) * log2(e), folded into Q at QKV epilogue

#define MFMA16(a, b, c) __builtin_amdgcn_mfma_f32_16x16x32_bf16((a), (b), (c), 0, 0, 0)
#define BAR()   __builtin_amdgcn_s_barrier()
#define LGKM0() asm volatile("s_waitcnt lgkmcnt(0)" ::: "memory")

__device__ __forceinline__ void gload_lds16(const void* g, void* l) {
  __builtin_amdgcn_global_load_lds((const __attribute__((address_space(1))) void*)g,
                                   (__attribute__((address_space(3))) void*)l, 16, 0, 0);
}

// ---------------- merged prep: x->bf16 cvt + W transposes (1 launch) ----------------
__device__ __forceinline__ void transpose_cvt_tile(const float* __restrict__ W,
                                                   bf16_t* __restrict__ WT,
                                                   int cols, int bx, int by) {
  __shared__ float tile[32][33];
  int j0 = bx * 32, i0 = by * 32;
  int c = threadIdx.x & 31, r0 = threadIdx.x >> 5;
#pragma unroll
  for (int it = 0; it < 4; ++it) {
    int r = r0 + it * 8;
    tile[r][c] = W[(long)(i0 + r) * cols + j0 + c];
  }
  __syncthreads();
#pragma unroll
  for (int it = 0; it < 4; ++it) {
    int r = r0 + it * 8;
    int orow = j0 + r, ocol = i0 + c;
    WT[(long)orow * 1024 + ((((ocol >> 3) ^ (orow & 7)) << 3) | (ocol & 7))] =
        (bf16_t)tile[c][r];
  }
}

__global__ __launch_bounds__(256) void k_prep(const float* __restrict__ x,
                                              bf16_t* __restrict__ xb,
                                              const float* __restrict__ Wq,
                                              bf16_t* __restrict__ WqT,
                                              const float* __restrict__ Wp,
                                              bf16_t* __restrict__ WpT) {
  int id = blockIdx.x;
  if (id < 2048) {                      // x -> bf16, 8 elems/thread, swizzled
    int i = (id * 256 + threadIdx.x) * 8;
    float4 a = *(const float4*)(x + i);
    float4 b = *(const float4*)(x + i + 4);
    bf16x8 v;
    v[0] = (bf16_t)a.x; v[1] = (bf16_t)a.y; v[2] = (bf16_t)a.z; v[3] = (bf16_t)a.w;
    v[4] = (bf16_t)b.x; v[5] = (bf16_t)b.y; v[6] = (bf16_t)b.z; v[7] = (bf16_t)b.w;
    int r = i >> 10, c = (i & 1023) >> 3;
    *(bf16x8*)(xb + r * 1024 + ((c ^ (r & 7)) << 3)) = v;
  } else if (id < 2048 + 3072) {        // W_qkv [1024][3072] -> WqT [3072][1024]
    int t = id - 2048;
    transpose_cvt_tile(Wq, WqT, 3072, t % 96, t / 96);
  } else {                              // W_proj [1024][1024] -> WpT
    int t = id - 5120;
    transpose_cvt_tile(Wp, WpT, 1024, t & 31, t >> 5);
  }
}

// ---------------- qkv GEMM: 256x192 8-phase + per-region LDS-bounce ---------
__global__ __launch_bounds__(512, 2) void k_gemm_qkv(const bf16_t* __restrict__ xb,
                                                     const bf16_t* __restrict__ WqT,
                                                     const float* __restrict__ bq,
                                                     bf16_t* __restrict__ Qb,
                                                     bf16_t* __restrict__ Kb,
                                                     bf16_t* __restrict__ Vt) {
  __shared__ alignas(16) bf16_t SH[57344];         // 112KB: A 2x16384 + B 2x12288
  const int t = threadIdx.x;
  const int w = t >> 6, lane = t & 63;
  const int l15 = lane & 15, g = lane >> 4;
  const int wm = w >> 2, wn = w & 3;               // wave: rows wm*128, cols wn*48
  const int xr = l15 & 7;

  // grid 256 = 16 bm x 16 bn; XCD (bid&7) owns 4bm x 8bn
  const int bid = blockIdx.x;
  const int xcd = bid & 7, ib = bid >> 3;          // ib in [0,32)
  const int bm = ((xcd & 3) * 4 + (ib & 3)) * 256;
  const int bn = ((xcd >> 2) * 8 + (ib >> 2)) * 192;

  const bf16_t* Ag = xb + (long)bm * 1024;
  const bf16_t* Bg = WqT + (long)bn * 1024;

  auto Asl = [&](int slot) -> bf16_t* { return SH + slot * 16384; };
  auto Bsl = [&](int slot) -> bf16_t* { return SH + 32768 + slot * 12288; };

  // one gload inst = 512 thr x 16B = 64 rows x 128B, linear LDS dest
  auto st1 = [&](bf16_t* lds, const bf16_t* gsrc, int row0, int kt) {
    gload_lds16(gsrc + (long)(row0 + (t >> 3)) * 1024 + kt * 64 + (t & 7) * 8,
                (char*)lds + row0 * 128 + t * 16);
  };
  auto evA0 = [&](int slot, int kt) {              // rows {0-63, 128-191}
    st1(Asl(slot), Ag, 0, kt);
    st1(Asl(slot), Ag, 128, kt);
  };
  auto evA1 = [&](int slot, int kt) {              // rows {64-127, 192-255}
    st1(Asl(slot), Ag, 64, kt);
    st1(Asl(slot), Ag, 192, kt);
  };
  auto evB = [&](int slot, int kt) {               // rows [0,192)
    st1(Bsl(slot), Bg, 0, kt);
    st1(Bsl(slot), Bg, 64, kt);
    st1(Bsl(slot), Bg, 128, kt);
  };

  f32x4 acc[8][3];
  const f32x4 vzero = {0.f, 0.f, 0.f, 0.f};
#pragma unroll
  for (int m = 0; m < 8; ++m)
#pragma unroll
    for (int n = 0; n < 3; ++n) acc[m][n] = vzero;

  bf16x8 bf[3][2], af[4][2];
  auto ldBn = [&](int slot, int n) {               // one B n-frag (2 ds_reads)
#pragma unroll
    for (int kk = 0; kk < 2; ++kk)
      bf[n][kk] = *(const bf16x8*)((const char*)Bsl(slot) +
                  (wn * 48 + n * 16 + l15) * 128 + (((kk * 4 + g) ^ xr) << 4));
  };
  auto ldA = [&](int slot, int half) {             // four A m-frags (8 ds_reads)
#pragma unroll
    for (int m = 0; m < 4; ++m)
#pragma unroll
      for (int kk = 0; kk < 2; ++kk)
        af[m][kk] = *(const bf16x8*)((const char*)Asl(slot) +
                    (wm * 128 + half * 64 + m * 16 + l15) * 128 +
                    (((kk * 4 + g) ^ xr) << 4));
  };
  auto mma2 = [&](int mb) {                        // a-half x n{0,1}: 16 MFMA
    __builtin_amdgcn_s_setprio(1);
#pragma unroll
    for (int m = 0; m < 4; ++m)
#pragma unroll
      for (int n = 0; n < 2; ++n)
#pragma unroll
        for (int kk = 0; kk < 2; ++kk)
          acc[mb + m][n] = MFMA16(af[m][kk], bf[n][kk], acc[mb + m][n]);
    __builtin_amdgcn_s_setprio(0);
  };
  auto mma1 = [&](int mb) {                        // a-half x n2: 8 MFMA
    __builtin_amdgcn_s_setprio(1);
#pragma unroll
    for (int m = 0; m < 4; ++m)
#pragma unroll
      for (int kk = 0; kk < 2; ++kk)
        acc[mb + m][2] = MFMA16(af[m][kk], bf[2][kk], acc[mb + m][2]);
    __builtin_amdgcn_s_setprio(0);
  };

  // prologue: tile0 full (7 gloads) + tile1's evB(3)+evA0(2); wait tile0 done
  evB(0, 0); evA0(0, 0); evA1(0, 0);
  evB(1, 1); evA0(1, 1);
  asm volatile("s_waitcnt vmcnt(5)" ::: "memory");
  BAR();

  for (int T = 0; T < 16; ++T) {
    const int h = T & 1;
    const bool stg = (T + 2) < 16;
    // ---- P1: evA1(T+1); regs <- B n0,n1 + A a0 ----
    if (T + 1 < 16) evA1(h ^ 1, T + 1);
    ldBn(h, 0); ldBn(h, 1); ldA(h, 0);
    BAR(); LGKM0();
    mma2(0);
    BAR();
    // ---- P2: regs <- B n2 ----
    ldBn(h, 2);
    BAR(); LGKM0();
    mma1(0);
    BAR();
    // ---- P3: regs <- A a1; stage evB(T+2) (B fully read by P2) ----
    ldA(h, 1);
    if (stg) evB(h, T + 2);
    BAR(); LGKM0();
    mma2(4);
    BAR();
    // ---- P4: stage evA0(T+2); counted wait ----
    if (stg) {
      evA0(h, T + 2);
      asm volatile("s_waitcnt vmcnt(5)" ::: "memory");
    } else {
      asm volatile("s_waitcnt vmcnt(0)" ::: "memory");
    }
    BAR();
    mma1(4);
    BAR();
  }

  // ---- epilogue: acc -> LDS (swizzled image, 3 regions x 32KB) -> stores ----
  const int bb = bm >> 11;
  const int tok0 = bm & 2047;
#pragma unroll
  for (int n = 0; n < 3; ++n) {
    int lc = wn * 48 + n * 16 + l15;               // local col, region-uniform
    int col = bn + lc;
    int t3 = col >> 10;
    int d = col & 63;
    int region = lc >> 6;
    float bias = bq[col];
#pragma unroll
    for (int m = 0; m < 8; ++m) {
#pragma unroll
      for (int r = 0; r < 4; ++r) {
        int ltok = wm * 128 + m * 16 + g * 4 + r;
        float val = acc[m][n][r] + bias;
        int off;
        if (t3 == 0) {
          off = ltok * 64 + d;
          val *= SCL2;
        } else if (t3 == 1) {
          int rr = ltok & 63;
          off = (ltok >> 6) * 4096 + rr * 64 + (((d >> 3) ^ (rr & 7)) << 3) + (d & 7);
        } else {
          int ct = ltok & 63;
          off = (ltok >> 6) * 4096 + d * 64 + (((ct >> 3) ^ (d & 7)) << 3) + (ct & 7);
        }
        SH[region * 16384 + off] = (bf16_t)val;
      }
    }
  }
  BAR();
#pragma unroll
  for (int hl = 0; hl < 3; ++hl) {
    int col0 = bn + hl * 64;
    int t3 = col0 >> 10;
    int hh = (col0 >> 6) & 15;
    bf16_t* dst = (t3 == 0) ? Qb : (t3 == 1 ? Kb : Vt);
    long tilebase = (t3 == 0) ? (long)tok0 * HD : (long)(tok0 >> 6) * 4096;
    long gbase = (long)(bb * NH + hh) * (NTOK * HD) + tilebase;
#pragma unroll
    for (int p = 0; p < 4; ++p) {
      bf16x8 vv = *(const bf16x8*)(SH + hl * 16384 + p * 4096 + t * 8);
      *(bf16x8*)(dst + gbase + p * 4096 + t * 8) = vv;
    }
  }
}

// ---------------- GEMM core (proj only), BK=64, counted-vmcnt dbuf ----------
__device__ __forceinline__ void gemm_core(const bf16_t* __restrict__ A,
                                          const bf16_t* __restrict__ B,
                                          int K, int bm, int bn,
                                          bf16_t* As, bf16_t* Bs, f32x4 acc[4][4]) {
  const int t = threadIdx.x;
  const int lane = t & 63;
  const int w = t >> 6;
  const int wr = (w >> 1) * 64, wc = (w & 1) * 64;
  const int l15 = lane & 15, g = lane >> 4;
  const int srow = t >> 3, scol = (t & 7) * 8;
  const f32x4 vzero = {0.f, 0.f, 0.f, 0.f};
#pragma unroll
  for (int m = 0; m < 4; ++m)
#pragma unroll
    for (int n = 0; n < 4; ++n) acc[m][n] = vzero;

  const bf16_t* ga = A + (long)(bm + srow) * K + scol;
  const bf16_t* gb = B + (long)(bn + srow) * K + scol;
  bf16_t* lA = As + srow * 64 + scol;
  bf16_t* lB = Bs + srow * 64 + scol;
  const int xr = l15 & 7;

  auto stageAB = [&](int buf, int k0) {
#pragma unroll
    for (int j = 0; j < 4; ++j) {
      gload_lds16(ga + (long)32 * j * K + k0, lA + buf * 8192 + j * 2048);
      gload_lds16(gb + (long)32 * j * K + k0, lB + buf * 8192 + j * 2048);
    }
  };

  const int nsteps = K >> 6;
  stageAB(0, 0);
  stageAB(1, 64);

  for (int s = 0; s < nsteps; ++s) {
    if (s == nsteps - 1) asm volatile("s_waitcnt vmcnt(0)" ::: "memory");
    else                 asm volatile("s_waitcnt vmcnt(8)" ::: "memory");
    __builtin_amdgcn_s_barrier();
    const char* Ab = (const char*)(As + (s & 1) * 8192);
    const char* Bb = (const char*)(Bs + (s & 1) * 8192);
#pragma unroll
    for (int kk = 0; kk < 2; ++kk) {
      bf16x8 af[4], bfv[4];
#pragma unroll
      for (int m = 0; m < 4; ++m)
        af[m] = *(const bf16x8*)(Ab + (wr + m * 16 + l15) * 128 +
                                 (((kk * 4 + g) ^ xr) << 4));
#pragma unroll
      for (int n = 0; n < 4; ++n)
        bfv[n] = *(const bf16x8*)(Bb + (wc + n * 16 + l15) * 128 +
                                  (((kk * 4 + g) ^ xr) << 4));
#pragma unroll
      for (int m = 0; m < 4; ++m)
#pragma unroll
        for (int n = 0; n < 4; ++n)
          acc[m][n] = MFMA16(af[m], bfv[n], acc[m][n]);
    }
    __builtin_amdgcn_s_barrier();
    if (s + 2 < nsteps) stageAB(s & 1, (s + 2) * 64);
  }
}

// ---------------- flash attention: 2-wave blocks, 4 blocks/CU ---------------
__global__ __launch_bounds__(128, 2) void k_attn(const bf16_t* __restrict__ Qb,
                                                 const bf16_t* __restrict__ Kb,
                                                 const bf16_t* __restrict__ Vt,
                                                 bf16_t* __restrict__ Ob) {
  __shared__ alignas(16) bf16_t Ks[2][64 * 64];   // 2 x 8KB, swizzled image
  __shared__ alignas(16) bf16_t Vs[2][64 * 64];   // 2 x 8KB, swizzled image
  __shared__ alignas(16) char  P2[2][4096];       // per-wave frag-major P (2 qf)

  const int b0 = blockIdx.x;
  const int swz = (b0 & 7) * 128 + (b0 >> 3);     // 128 consecutive blocks/XCD
  const int qt = swz & 31, bh = swz >> 5;         // 32 q-tiles of 64 rows/head
  const int b = bh >> 4, h = bh & 15;
  const int t = threadIdx.x;
  const int w = t >> 6, lane = t & 63;
  const int l15 = lane & 15, g = lane >> 4;
  const bf16_t* Qp = Qb + bh * (NTOK * HD);
  const bf16_t* Kp = Kb + bh * (NTOK * HD);       // 32 tiles x 4096 elems
  const bf16_t* Vp = Vt + bh * (NTOK * HD);
  const int q0 = qt * 64 + w * 32;                // wave's 32 q-rows
  char* P2w = &P2[w][0];

  // frag-read swizzle: chunk g of row (..+l15) is at byte ((g ^ (l15&7))<<4)
  const int cs0 = ((g ^ (l15 & 7)) << 4);
  const int cs1 = cs0 ^ 64;                       // k-half 1 (chunk 4+g)

  bf16x8 qfr[2][2];
#pragma unroll
  for (int qf = 0; qf < 2; ++qf)
#pragma unroll
    for (int kk = 0; kk < 2; ++kk)
      qfr[qf][kk] = *(const bf16x8*)(Qp + (q0 + qf * 16 + l15) * HD + kk * 32 + g * 8);

  bf16x8 ones;
#pragma unroll
  for (int i = 0; i < 8; ++i) ones[i] = (bf16_t)1.0f;

  const f32x4 vzero = {0.f, 0.f, 0.f, 0.f};
  f32x4 o[2][4];
#pragma unroll
  for (int qf = 0; qf < 2; ++qf)
#pragma unroll
    for (int df = 0; df < 4; ++df) o[qf][df] = vzero;
  f32x4 o_sum[2] = {vzero, vzero};

  // staging: 128 threads move one 8KB K-tile + 8KB V-tile (8 gloads/thread)
  auto stage = [&](int buf, int tile) {
    const bf16_t* gk = Kp + tile * 4096 + t * 8;
    const bf16_t* gv = Vp + tile * 4096 + t * 8;
#pragma unroll
    for (int j = 0; j < 4; ++j) {
      gload_lds16(gk + j * 1024, (char*)Ks[buf] + j * 2048 + t * 16);
      gload_lds16(gv + j * 1024, (char*)Vs[buf] + j * 2048 + t * 16);
    }
  };

  stage(0, 0);
  stage(1, 1);

  for (int i = 0; i < 32; ++i) {
    if (i == 31) asm volatile("s_waitcnt vmcnt(0)" ::: "memory");
    else         asm volatile("s_waitcnt vmcnt(8)" ::: "memory");
    __builtin_amdgcn_s_barrier();
    const char* kbuf = (const char*)Ks[i & 1];
    const char* vbuf = (const char*)Vs[i & 1];
    // ---- S^T = K * Q^T, both q-frags share each K-frag read ----
    f32x4 s[2][4];
    __builtin_amdgcn_s_setprio(1);
#pragma unroll
    for (int kf = 0; kf < 4; ++kf) {
      int rb = (kf * 16 + l15) * 128;
      bf16x8 ka0 = *(const bf16x8*)(kbuf + rb + cs0);
      bf16x8 ka1 = *(const bf16x8*)(kbuf + rb + cs1);
      s[0][kf] = MFMA16(ka0, qfr[0][0], vzero);
      s[1][kf] = MFMA16(ka0, qfr[1][0], vzero);
      s[0][kf] = MFMA16(ka1, qfr[0][1], s[0][kf]);
      s[1][kf] = MFMA16(ka1, qfr[1][1], s[1][kf]);
    }
    __builtin_amdgcn_s_setprio(0);
    // ---- softmax numerator: P = exp2(S), raw HW exp2, no max pass ----
#pragma unroll
    for (int qf = 0; qf < 2; ++qf)
#pragma unroll
      for (int kf = 0; kf < 4; ++kf) {
        bf16x4 pw;
        pw[0] = (bf16_t)__builtin_amdgcn_exp2f(s[qf][kf][0]);
        pw[1] = (bf16_t)__builtin_amdgcn_exp2f(s[qf][kf][1]);
        pw[2] = (bf16_t)__builtin_amdgcn_exp2f(s[qf][kf][2]);
        pw[3] = (bf16_t)__builtin_amdgcn_exp2f(s[qf][kf][3]);
        *(bf16x4*)(P2w + qf * 2048 + (2 * kf + (g >> 1)) * 256 + l15 * 16 + 8 * (g & 1)) = pw;
      }
    // ---- O^T += V * P^T ; V-frag reads shared across q-frags ----
    __builtin_amdgcn_s_setprio(1);
#pragma unroll
    for (int kb = 0; kb < 2; ++kb) {
      bf16x8 pf0 = *(const bf16x8*)(P2w + kb * 1024 + lane * 16);
      bf16x8 pf1 = *(const bf16x8*)(P2w + 2048 + kb * 1024 + lane * 16);
      int csk = kb ? cs1 : cs0;
      o_sum[0] = MFMA16(ones, pf0, o_sum[0]);
      o_sum[1] = MFMA16(ones, pf1, o_sum[1]);
#pragma unroll
      for (int df = 0; df < 4; ++df) {
        bf16x8 va = *(const bf16x8*)(vbuf + (df * 16 + l15) * 128 + csk);
        o[0][df] = MFMA16(va, pf0, o[0][df]);
        o[1][df] = MFMA16(va, pf1, o[1][df]);
      }
    }
    __builtin_amdgcn_s_setprio(0);
    __builtin_amdgcn_s_barrier();
    if (i + 2 < 32) stage(i & 1, i + 2);
  }
  // ---- normalize + write O swizzled (feeds gemm_proj's A operand) ----
#pragma unroll
  for (int qf = 0; qf < 2; ++qf) {
    float inv = 1.0f / o_sum[qf][0];
    int tok = q0 + qf * 16 + l15;
    bf16_t* oprow = Ob + (long)(b * NTOK + tok) * DIM;
    const int xr = l15 & 7;                        // tok&7 == l15&7 (q0 mult of 32)
#pragma unroll
    for (int df = 0; df < 4; ++df) {
#pragma unroll
      for (int rp = 0; rp < 2; ++rp) {
        bf16x2 v2;
        v2[0] = (bf16_t)(o[qf][df][rp * 2]     * inv);
        v2[1] = (bf16_t)(o[qf][df][rp * 2 + 1] * inv);
        int c = h * 8 + df * 2 + (g >> 1);
        *(bf16x2*)(oprow + ((c ^ xr) << 3) + (g & 1) * 4 + rp * 2) = v2;
      }
    }
  }
}

// ---------------- GEMM2: out = O @ W_proj + b (fp32 out) ----------------
__global__ __launch_bounds__(256) void k_gemm_proj(const bf16_t* __restrict__ Ob,
                                                   const bf16_t* __restrict__ WpT,
                                                   const float* __restrict__ bp,
                                                   float* __restrict__ out) {
  __shared__ alignas(16) bf16_t As[2 * 128 * 64];
  __shared__ alignas(16) bf16_t Bs[2 * 128 * 64];
  f32x4 acc[4][4];
  const int bid = blockIdx.x;
  const int bn = (bid & 7) * 128;
  const int bm = (bid >> 3) * 128;
  gemm_core(Ob, WpT, DIM, bm, bn, As, Bs, acc);

  const int lane = threadIdx.x & 63, w = threadIdx.x >> 6;
  const int wr = (w >> 1) * 64, wc = (w & 1) * 64;
  const int l15 = lane & 15, g = lane >> 4;
#pragma unroll
  for (int n = 0; n < 4; ++n) {
    int col = bn + wc + n * 16 + l15;
    float bias = bp[col];
#pragma unroll
    for (int m = 0; m < 4; ++m) {
      int rowb = bm + wr + m * 16 + g * 4;
#pragma unroll
      for (int r = 0; r < 4; ++r)
        out[(long)(rowb + r) * DIM + col] = acc[m][n][r] + bias;
    }
  }
}

// ---------------------------------------------------------------------------
extern "C" void kernel_launch(void* const* d_in, const int* in_sizes, int n_in,
                              void* d_out, int out_size, void* d_ws, size_t ws_size,
                              hipStream_t stream) {
  const float* x     = (const float*)d_in[0];
  const float* Wqkv  = (const float*)d_in[1];
  const float* bqkv  = (const float*)d_in[2];
  const float* Wproj = (const float*)d_in[3];
  const float* bproj = (const float*)d_in[4];
  float* out = (float*)d_out;

  char* ws = (char*)d_ws;
  bf16_t* xb  = (bf16_t*)(ws);                    // 8 MB (swizzled)
  bf16_t* WqT = (bf16_t*)(ws + (8l  << 20));      // 6 MB (swizzled)
  bf16_t* WpT = (bf16_t*)(ws + (14l << 20));      // 2 MB (swizzled)
  bf16_t* Qb  = (bf16_t*)(ws + (16l << 20));      // 8 MB
  bf16_t* Kb  = (bf16_t*)(ws + (24l << 20));      // 8 MB (swizzled tiles)
  bf16_t* Vt  = (bf16_t*)(ws + (32l << 20));      // 8 MB (swizzled tiles)
  bf16_t* Ob  = (bf16_t*)(ws);                    // aliases xb (swizzled)

  k_prep<<<6144, 256, 0, stream>>>(x, xb, Wqkv, WqT, Wproj, WpT);
  k_gemm_qkv<<<256, 512, 0, stream>>>(xb, WqT, bqkv, Qb, Kb, Vt);
  k_attn<<<1024, 128, 0, stream>>>(Qb, Kb, Vt, Ob);
  k_gemm_proj<<<256, 256, 0, stream>>>(Ob, WpT, bproj, out);
}

// Round 21
// 105.046 us; speedup vs baseline: 1.0577x; 1.0577x over previous
//
#include <hip/hip_runtime.h>

// ---------------------------------------------------------------------------
// Fused attention block, bf16 MFMA pipeline.
// ws layout (needs 40 MB):
//   [0,8M)    xb   : x as bf16 [4096][1024], ROW-CHUNK-SWIZZLED (reused as Ob)
//   [8M,14M)  WqT  : W_qkv^T bf16 [3072][1024], swizzled
//   [14M,16M) WpT  : W_proj^T bf16 [1024][1024], swizzled
//   [16M,24M) Qb   : [32][2048][64] bf16  (pre-scaled by SCALE*log2e)
//   [24M,32M) Kb   : [32][32 tiles][64x64] bf16, XOR-chunk-swizzled tiles
//   [32M,40M) Vt   : [32][32 tiles][64x64] bf16, transposed + swizzled tiles
//
// ROW-CHUNK SWIZZLE (GEMM operands, row length 1024): element (r,d) stored at
//   r*1024 + (((d>>3) ^ (r&7))<<3) + (d&7)  -> 0 LDS bank conflicts (R12).
//
// qkv GEMM (R19): 256x192 tile, grid 256 = exactly 1 block/CU, 8-phase
// counted-vmcnt schedule, per-region LDS-bounce epilogue.
// attn: R18 config (best measured 47us) -- 4-wave blocks, 128 q-rows, grid
// 512, counted-vmcnt dbuf. R20's 2-wave split proved attn is traffic-bound.
// prep (R21): transpose writes packed as bf16x4 (8B) -- kills scalar-store
// RMW inflation on the 8MB of W outputs.
// ---------------------------------------------------------------------------

typedef __bf16 bf16_t;
typedef __bf16 bf16x2 __attribute__((ext_vector_type(2)));
typedef __bf16 bf16x4 __attribute__((ext_vector_type(4)));
typedef __bf16 bf16x8 __attribute__((ext_vector_type(8)));
typedef float  f32x4  __attribute__((ext_vector_type(4)));

#define NTOK 2048
#define DIM  1024
#define NH   16
#define HD   64
#define SCL2 0.18033688011112042f   // (1/8) * log2(e), folded into Q at QKV epilogue

#define MFMA16(a, b, c) __builtin_amdgcn_mfma_f32_16x16x32_bf16((a), (b), (c), 0, 0, 0)
#define BAR()   __builtin_amdgcn_s_barrier()
#define LGKM0() asm volatile("s_waitcnt lgkmcnt(0)" ::: "memory")

__device__ __forceinline__ void gload_lds16(const void* g, void* l) {
  __builtin_amdgcn_global_load_lds((const __attribute__((address_space(1))) void*)g,
                                   (__attribute__((address_space(3))) void*)l, 16, 0, 0);
}

// ---------------- merged prep: x->bf16 cvt + W transposes (1 launch) ----------------
// Transpose write phase: thread t owns 4 consecutive ocols of one output row
// (orow = j0 + (t>>3), ocol = i0 + (t&7)*4) -> one 8B bf16x4 store, aligned
// within a swizzle chunk (chunk granularity 8 elems).
__device__ __forceinline__ void transpose_cvt_tile(const float* __restrict__ W,
                                                   bf16_t* __restrict__ WT,
                                                   int cols, int bx, int by) {
  __shared__ float tile[32][33];
  int j0 = bx * 32, i0 = by * 32;
  int c = threadIdx.x & 31, r0 = threadIdx.x >> 5;
#pragma unroll
  for (int it = 0; it < 4; ++it) {
    int r = r0 + it * 8;
    tile[r][c] = W[(long)(i0 + r) * cols + j0 + c];
  }
  __syncthreads();
  int orl = threadIdx.x >> 3, sub = threadIdx.x & 7;
  int orow = j0 + orl;
  bf16x4 v;
#pragma unroll
  for (int u = 0; u < 4; ++u) v[u] = (bf16_t)tile[sub * 4 + u][orl];
  int chunk_g = (i0 >> 3) + (sub >> 1);
  *(bf16x4*)(WT + (long)orow * 1024 + ((chunk_g ^ (orow & 7)) << 3) + (sub & 1) * 4) = v;
}

__global__ __launch_bounds__(256) void k_prep(const float* __restrict__ x,
                                              bf16_t* __restrict__ xb,
                                              const float* __restrict__ Wq,
                                              bf16_t* __restrict__ WqT,
                                              const float* __restrict__ Wp,
                                              bf16_t* __restrict__ WpT) {
  int id = blockIdx.x;
  if (id < 2048) {                      // x -> bf16, 8 elems/thread, swizzled
    int i = (id * 256 + threadIdx.x) * 8;
    float4 a = *(const float4*)(x + i);
    float4 b = *(const float4*)(x + i + 4);
    bf16x8 v;
    v[0] = (bf16_t)a.x; v[1] = (bf16_t)a.y; v[2] = (bf16_t)a.z; v[3] = (bf16_t)a.w;
    v[4] = (bf16_t)b.x; v[5] = (bf16_t)b.y; v[6] = (bf16_t)b.z; v[7] = (bf16_t)b.w;
    int r = i >> 10, c = (i & 1023) >> 3;
    *(bf16x8*)(xb + r * 1024 + ((c ^ (r & 7)) << 3)) = v;
  } else if (id < 2048 + 3072) {        // W_qkv [1024][3072] -> WqT [3072][1024]
    int t = id - 2048;
    transpose_cvt_tile(Wq, WqT, 3072, t % 96, t / 96);
  } else {                              // W_proj [1024][1024] -> WpT
    int t = id - 5120;
    transpose_cvt_tile(Wp, WpT, 1024, t & 31, t >> 5);
  }
}

// ---------------- qkv GEMM: 256x192 8-phase + per-region LDS-bounce ---------
__global__ __launch_bounds__(512, 2) void k_gemm_qkv(const bf16_t* __restrict__ xb,
                                                     const bf16_t* __restrict__ WqT,
                                                     const float* __restrict__ bq,
                                                     bf16_t* __restrict__ Qb,
                                                     bf16_t* __restrict__ Kb,
                                                     bf16_t* __restrict__ Vt) {
  __shared__ alignas(16) bf16_t SH[57344];         // 112KB: A 2x16384 + B 2x12288
  const int t = threadIdx.x;
  const int w = t >> 6, lane = t & 63;
  const int l15 = lane & 15, g = lane >> 4;
  const int wm = w >> 2, wn = w & 3;               // wave: rows wm*128, cols wn*48
  const int xr = l15 & 7;

  // grid 256 = 16 bm x 16 bn; XCD (bid&7) owns 4bm x 8bn
  const int bid = blockIdx.x;
  const int xcd = bid & 7, ib = bid >> 3;          // ib in [0,32)
  const int bm = ((xcd & 3) * 4 + (ib & 3)) * 256;
  const int bn = ((xcd >> 2) * 8 + (ib >> 2)) * 192;

  const bf16_t* Ag = xb + (long)bm * 1024;
  const bf16_t* Bg = WqT + (long)bn * 1024;

  auto Asl = [&](int slot) -> bf16_t* { return SH + slot * 16384; };
  auto Bsl = [&](int slot) -> bf16_t* { return SH + 32768 + slot * 12288; };

  // one gload inst = 512 thr x 16B = 64 rows x 128B, linear LDS dest
  auto st1 = [&](bf16_t* lds, const bf16_t* gsrc, int row0, int kt) {
    gload_lds16(gsrc + (long)(row0 + (t >> 3)) * 1024 + kt * 64 + (t & 7) * 8,
                (char*)lds + row0 * 128 + t * 16);
  };
  auto evA0 = [&](int slot, int kt) {              // rows {0-63, 128-191}
    st1(Asl(slot), Ag, 0, kt);
    st1(Asl(slot), Ag, 128, kt);
  };
  auto evA1 = [&](int slot, int kt) {              // rows {64-127, 192-255}
    st1(Asl(slot), Ag, 64, kt);
    st1(Asl(slot), Ag, 192, kt);
  };
  auto evB = [&](int slot, int kt) {               // rows [0,192)
    st1(Bsl(slot), Bg, 0, kt);
    st1(Bsl(slot), Bg, 64, kt);
    st1(Bsl(slot), Bg, 128, kt);
  };

  f32x4 acc[8][3];
  const f32x4 vzero = {0.f, 0.f, 0.f, 0.f};
#pragma unroll
  for (int m = 0; m < 8; ++m)
#pragma unroll
    for (int n = 0; n < 3; ++n) acc[m][n] = vzero;

  bf16x8 bf[3][2], af[4][2];
  auto ldBn = [&](int slot, int n) {               // one B n-frag (2 ds_reads)
#pragma unroll
    for (int kk = 0; kk < 2; ++kk)
      bf[n][kk] = *(const bf16x8*)((const char*)Bsl(slot) +
                  (wn * 48 + n * 16 + l15) * 128 + (((kk * 4 + g) ^ xr) << 4));
  };
  auto ldA = [&](int slot, int half) {             // four A m-frags (8 ds_reads)
#pragma unroll
    for (int m = 0; m < 4; ++m)
#pragma unroll
      for (int kk = 0; kk < 2; ++kk)
        af[m][kk] = *(const bf16x8*)((const char*)Asl(slot) +
                    (wm * 128 + half * 64 + m * 16 + l15) * 128 +
                    (((kk * 4 + g) ^ xr) << 4));
  };
  auto mma2 = [&](int mb) {                        // a-half x n{0,1}: 16 MFMA
    __builtin_amdgcn_s_setprio(1);
#pragma unroll
    for (int m = 0; m < 4; ++m)
#pragma unroll
      for (int n = 0; n < 2; ++n)
#pragma unroll
        for (int kk = 0; kk < 2; ++kk)
          acc[mb + m][n] = MFMA16(af[m][kk], bf[n][kk], acc[mb + m][n]);
    __builtin_amdgcn_s_setprio(0);
  };
  auto mma1 = [&](int mb) {                        // a-half x n2: 8 MFMA
    __builtin_amdgcn_s_setprio(1);
#pragma unroll
    for (int m = 0; m < 4; ++m)
#pragma unroll
      for (int kk = 0; kk < 2; ++kk)
        acc[mb + m][2] = MFMA16(af[m][kk], bf[2][kk], acc[mb + m][2]);
    __builtin_amdgcn_s_setprio(0);
  };

  // prologue: tile0 full (7 gloads) + tile1's evB(3)+evA0(2); wait tile0 done
  evB(0, 0); evA0(0, 0); evA1(0, 0);
  evB(1, 1); evA0(1, 1);
  asm volatile("s_waitcnt vmcnt(5)" ::: "memory");
  BAR();

  for (int T = 0; T < 16; ++T) {
    const int h = T & 1;
    const bool stg = (T + 2) < 16;
    // ---- P1: evA1(T+1); regs <- B n0,n1 + A a0 ----
    if (T + 1 < 16) evA1(h ^ 1, T + 1);
    ldBn(h, 0); ldBn(h, 1); ldA(h, 0);
    BAR(); LGKM0();
    mma2(0);
    BAR();
    // ---- P2: regs <- B n2 ----
    ldBn(h, 2);
    BAR(); LGKM0();
    mma1(0);
    BAR();
    // ---- P3: regs <- A a1; stage evB(T+2) (B fully read by P2) ----
    ldA(h, 1);
    if (stg) evB(h, T + 2);
    BAR(); LGKM0();
    mma2(4);
    BAR();
    // ---- P4: stage evA0(T+2); counted wait ----
    if (stg) {
      evA0(h, T + 2);
      asm volatile("s_waitcnt vmcnt(5)" ::: "memory");
    } else {
      asm volatile("s_waitcnt vmcnt(0)" ::: "memory");
    }
    BAR();
    mma1(4);
    BAR();
  }

  // ---- epilogue: acc -> LDS (swizzled image, 3 regions x 32KB) -> stores ----
  const int bb = bm >> 11;
  const int tok0 = bm & 2047;
#pragma unroll
  for (int n = 0; n < 3; ++n) {
    int lc = wn * 48 + n * 16 + l15;               // local col, region-uniform
    int col = bn + lc;
    int t3 = col >> 10;
    int d = col & 63;
    int region = lc >> 6;
    float bias = bq[col];
#pragma unroll
    for (int m = 0; m < 8; ++m) {
#pragma unroll
      for (int r = 0; r < 4; ++r) {
        int ltok = wm * 128 + m * 16 + g * 4 + r;
        float val = acc[m][n][r] + bias;
        int off;
        if (t3 == 0) {
          off = ltok * 64 + d;
          val *= SCL2;
        } else if (t3 == 1) {
          int rr = ltok & 63;
          off = (ltok >> 6) * 4096 + rr * 64 + (((d >> 3) ^ (rr & 7)) << 3) + (d & 7);
        } else {
          int ct = ltok & 63;
          off = (ltok >> 6) * 4096 + d * 64 + (((ct >> 3) ^ (d & 7)) << 3) + (ct & 7);
        }
        SH[region * 16384 + off] = (bf16_t)val;
      }
    }
  }
  BAR();
#pragma unroll
  for (int hl = 0; hl < 3; ++hl) {
    int col0 = bn + hl * 64;
    int t3 = col0 >> 10;
    int hh = (col0 >> 6) & 15;
    bf16_t* dst = (t3 == 0) ? Qb : (t3 == 1 ? Kb : Vt);
    long tilebase = (t3 == 0) ? (long)tok0 * HD : (long)(tok0 >> 6) * 4096;
    long gbase = (long)(bb * NH + hh) * (NTOK * HD) + tilebase;
#pragma unroll
    for (int p = 0; p < 4; ++p) {
      bf16x8 vv = *(const bf16x8*)(SH + hl * 16384 + p * 4096 + t * 8);
      *(bf16x8*)(dst + gbase + p * 4096 + t * 8) = vv;
    }
  }
}

// ---------------- GEMM core (proj only), BK=64, counted-vmcnt dbuf ----------
__device__ __forceinline__ void gemm_core(const bf16_t* __restrict__ A,
                                          const bf16_t* __restrict__ B,
                                          int K, int bm, int bn,
                                          bf16_t* As, bf16_t* Bs, f32x4 acc[4][4]) {
  const int t = threadIdx.x;
  const int lane = t & 63;
  const int w = t >> 6;
  const int wr = (w >> 1) * 64, wc = (w & 1) * 64;
  const int l15 = lane & 15, g = lane >> 4;
  const int srow = t >> 3, scol = (t & 7) * 8;
  const f32x4 vzero = {0.f, 0.f, 0.f, 0.f};
#pragma unroll
  for (int m = 0; m < 4; ++m)
#pragma unroll
    for (int n = 0; n < 4; ++n) acc[m][n] = vzero;

  const bf16_t* ga = A + (long)(bm + srow) * K + scol;
  const bf16_t* gb = B + (long)(bn + srow) * K + scol;
  bf16_t* lA = As + srow * 64 + scol;
  bf16_t* lB = Bs + srow * 64 + scol;
  const int xr = l15 & 7;

  auto stageAB = [&](int buf, int k0) {
#pragma unroll
    for (int j = 0; j < 4; ++j) {
      gload_lds16(ga + (long)32 * j * K + k0, lA + buf * 8192 + j * 2048);
      gload_lds16(gb + (long)32 * j * K + k0, lB + buf * 8192 + j * 2048);
    }
  };

  const int nsteps = K >> 6;
  stageAB(0, 0);
  stageAB(1, 64);

  for (int s = 0; s < nsteps; ++s) {
    if (s == nsteps - 1) asm volatile("s_waitcnt vmcnt(0)" ::: "memory");
    else                 asm volatile("s_waitcnt vmcnt(8)" ::: "memory");
    __builtin_amdgcn_s_barrier();
    const char* Ab = (const char*)(As + (s & 1) * 8192);
    const char* Bb = (const char*)(Bs + (s & 1) * 8192);
#pragma unroll
    for (int kk = 0; kk < 2; ++kk) {
      bf16x8 af[4], bfv[4];
#pragma unroll
      for (int m = 0; m < 4; ++m)
        af[m] = *(const bf16x8*)(Ab + (wr + m * 16 + l15) * 128 +
                                 (((kk * 4 + g) ^ xr) << 4));
#pragma unroll
      for (int n = 0; n < 4; ++n)
        bfv[n] = *(const bf16x8*)(Bb + (wc + n * 16 + l15) * 128 +
                                  (((kk * 4 + g) ^ xr) << 4));
#pragma unroll
      for (int m = 0; m < 4; ++m)
#pragma unroll
        for (int n = 0; n < 4; ++n)
          acc[m][n] = MFMA16(af[m], bfv[n], acc[m][n]);
    }
    __builtin_amdgcn_s_barrier();
    if (s + 2 < nsteps) stageAB(s & 1, (s + 2) * 64);
  }
}

// ---------------- flash attention (R18 config: best measured 47us) ----------
__global__ __launch_bounds__(256, 3) void k_attn(const bf16_t* __restrict__ Qb,
                                                 const bf16_t* __restrict__ Kb,
                                                 const bf16_t* __restrict__ Vt,
                                                 bf16_t* __restrict__ Ob) {
  __shared__ alignas(16) bf16_t Ks[2][64 * 64];
  __shared__ alignas(16) bf16_t Vs[2][64 * 64];
  __shared__ alignas(16) char  P2[4][4096];

  const int b0 = blockIdx.x;
  const int swz = (b0 & 7) * 64 + (b0 >> 3);
  const int qt = swz & 15, bh = swz >> 4;
  const int b = bh >> 4, h = bh & 15;
  const int t = threadIdx.x;
  const int w = t >> 6, lane = t & 63;
  const int l15 = lane & 15, g = lane >> 4;
  const bf16_t* Qp = Qb + bh * (NTOK * HD);
  const bf16_t* Kp = Kb + bh * (NTOK * HD);
  const bf16_t* Vp = Vt + bh * (NTOK * HD);
  const int q0 = qt * 128 + w * 32;
  char* P2w = &P2[w][0];

  const int cs0 = ((g ^ (l15 & 7)) << 4);
  const int cs1 = cs0 ^ 64;

  bf16x8 qfr[2][2];
#pragma unroll
  for (int qf = 0; qf < 2; ++qf)
#pragma unroll
    for (int kk = 0; kk < 2; ++kk)
      qfr[qf][kk] = *(const bf16x8*)(Qp + (q0 + qf * 16 + l15) * HD + kk * 32 + g * 8);

  bf16x8 ones;
#pragma unroll
  for (int i = 0; i < 8; ++i) ones[i] = (bf16_t)1.0f;

  const f32x4 vzero = {0.f, 0.f, 0.f, 0.f};
  f32x4 o[2][4];
#pragma unroll
  for (int qf = 0; qf < 2; ++qf)
#pragma unroll
    for (int df = 0; df < 4; ++df) o[qf][df] = vzero;
  f32x4 o_sum[2] = {vzero, vzero};

  auto stage = [&](int buf, int tile) {
    const bf16_t* gk = Kp + tile * 4096 + t * 8;
    const bf16_t* gv = Vp + tile * 4096 + t * 8;
    gload_lds16(gk,        (char*)Ks[buf] + t * 16);
    gload_lds16(gk + 2048, (char*)Ks[buf] + 4096 + t * 16);
    gload_lds16(gv,        (char*)Vs[buf] + t * 16);
    gload_lds16(gv + 2048, (char*)Vs[buf] + 4096 + t * 16);
  };

  stage(0, 0);
  stage(1, 1);

  for (int i = 0; i < 32; ++i) {
    if (i == 31) asm volatile("s_waitcnt vmcnt(0)" ::: "memory");
    else         asm volatile("s_waitcnt vmcnt(4)" ::: "memory");
    __builtin_amdgcn_s_barrier();
    const char* kbuf = (const char*)Ks[i & 1];
    const char* vbuf = (const char*)Vs[i & 1];
    f32x4 s[2][4];
    __builtin_amdgcn_s_setprio(1);
#pragma unroll
    for (int kf = 0; kf < 4; ++kf) {
      int rb = (kf * 16 + l15) * 128;
      bf16x8 ka0 = *(const bf16x8*)(kbuf + rb + cs0);
      bf16x8 ka1 = *(const bf16x8*)(kbuf + rb + cs1);
      s[0][kf] = MFMA16(ka0, qfr[0][0], vzero);
      s[1][kf] = MFMA16(ka0, qfr[1][0], vzero);
      s[0][kf] = MFMA16(ka1, qfr[0][1], s[0][kf]);
      s[1][kf] = MFMA16(ka1, qfr[1][1], s[1][kf]);
    }
    __builtin_amdgcn_s_setprio(0);
#pragma unroll
    for (int qf = 0; qf < 2; ++qf)
#pragma unroll
      for (int kf = 0; kf < 4; ++kf) {
        bf16x4 pw;
        pw[0] = (bf16_t)__builtin_amdgcn_exp2f(s[qf][kf][0]);
        pw[1] = (bf16_t)__builtin_amdgcn_exp2f(s[qf][kf][1]);
        pw[2] = (bf16_t)__builtin_amdgcn_exp2f(s[qf][kf][2]);
        pw[3] = (bf16_t)__builtin_amdgcn_exp2f(s[qf][kf][3]);
        *(bf16x4*)(P2w + qf * 2048 + (2 * kf + (g >> 1)) * 256 + l15 * 16 + 8 * (g & 1)) = pw;
      }
    __builtin_amdgcn_s_setprio(1);
#pragma unroll
    for (int kb = 0; kb < 2; ++kb) {
      bf16x8 pf0 = *(const bf16x8*)(P2w + kb * 1024 + lane * 16);
      bf16x8 pf1 = *(const bf16x8*)(P2w + 2048 + kb * 1024 + lane * 16);
      int csk = kb ? cs1 : cs0;
      o_sum[0] = MFMA16(ones, pf0, o_sum[0]);
      o_sum[1] = MFMA16(ones, pf1, o_sum[1]);
#pragma unroll
      for (int df = 0; df < 4; ++df) {
        bf16x8 va = *(const bf16x8*)(vbuf + (df * 16 + l15) * 128 + csk);
        o[0][df] = MFMA16(va, pf0, o[0][df]);
        o[1][df] = MFMA16(va, pf1, o[1][df]);
      }
    }
    __builtin_amdgcn_s_setprio(0);
    __builtin_amdgcn_s_barrier();
    if (i + 2 < 32) stage(i & 1, i + 2);
  }
#pragma unroll
  for (int qf = 0; qf < 2; ++qf) {
    float inv = 1.0f / o_sum[qf][0];
    int tok = q0 + qf * 16 + l15;
    bf16_t* oprow = Ob + (long)(b * NTOK + tok) * DIM;
    const int xr = l15 & 7;
#pragma unroll
    for (int df = 0; df < 4; ++df) {
#pragma unroll
      for (int rp = 0; rp < 2; ++rp) {
        bf16x2 v2;
        v2[0] = (bf16_t)(o[qf][df][rp * 2]     * inv);
        v2[1] = (bf16_t)(o[qf][df][rp * 2 + 1] * inv);
        int c = h * 8 + df * 2 + (g >> 1);
        *(bf16x2*)(oprow + ((c ^ xr) << 3) + (g & 1) * 4 + rp * 2) = v2;
      }
    }
  }
}

// ---------------- GEMM2: out = O @ W_proj + b (fp32 out) ----------------
__global__ __launch_bounds__(256) void k_gemm_proj(const bf16_t* __restrict__ Ob,
                                                   const bf16_t* __restrict__ WpT,
                                                   const float* __restrict__ bp,
                                                   float* __restrict__ out) {
  __shared__ alignas(16) bf16_t As[2 * 128 * 64];
  __shared__ alignas(16) bf16_t Bs[2 * 128 * 64];
  f32x4 acc[4][4];
  const int bid = blockIdx.x;
  const int bn = (bid & 7) * 128;
  const int bm = (bid >> 3) * 128;
  gemm_core(Ob, WpT, DIM, bm, bn, As, Bs, acc);

  const int lane = threadIdx.x & 63, w = threadIdx.x >> 6;
  const int wr = (w >> 1) * 64, wc = (w & 1) * 64;
  const int l15 = lane & 15, g = lane >> 4;
#pragma unroll
  for (int n = 0; n < 4; ++n) {
    int col = bn + wc + n * 16 + l15;
    float bias = bp[col];
#pragma unroll
    for (int m = 0; m < 4; ++m) {
      int rowb = bm + wr + m * 16 + g * 4;
#pragma unroll
      for (int r = 0; r < 4; ++r)
        out[(long)(rowb + r) * DIM + col] = acc[m][n][r] + bias;
    }
  }
}

// ---------------------------------------------------------------------------
extern "C" void kernel_launch(void* const* d_in, const int* in_sizes, int n_in,
                              void* d_out, int out_size, void* d_ws, size_t ws_size,
                              hipStream_t stream) {
  const float* x     = (const float*)d_in[0];
  const float* Wqkv  = (const float*)d_in[1];
  const float* bqkv  = (const float*)d_in[2];
  const float* Wproj = (const float*)d_in[3];
  const float* bproj = (const float*)d_in[4];
  float* out = (float*)d_out;

  char* ws = (char*)d_ws;
  bf16_t* xb  = (bf16_t*)(ws);                    // 8 MB (swizzled)
  bf16_t* WqT = (bf16_t*)(ws + (8l  << 20));      // 6 MB (swizzled)
  bf16_t* WpT = (bf16_t*)(ws + (14l << 20));      // 2 MB (swizzled)
  bf16_t* Qb  = (bf16_t*)(ws + (16l << 20));      // 8 MB
  bf16_t* Kb  = (bf16_t*)(ws + (24l << 20));      // 8 MB (swizzled tiles)
  bf16_t* Vt  = (bf16_t*)(ws + (32l << 20));      // 8 MB (swizzled tiles)
  bf16_t* Ob  = (bf16_t*)(ws);                    // aliases xb (swizzled)

  k_prep<<<6144, 256, 0, stream>>>(x, xb, Wqkv, WqT, Wproj, WpT);
  k_gemm_qkv<<<256, 512, 0, stream>>>(xb, WqT, bqkv, Qb, Kb, Vt);
  k_attn<<<512, 256, 0, stream>>>(Qb, Kb, Vt, Ob);
  k_gemm_proj<<<256, 256, 0, stream>>>(Ob, WpT, bproj, out);
}